// Round 9
// baseline (267.055 us; speedup 1.0000x reference)
//
#include <hip/hip_runtime.h>

#define N_NODES 100000
#define N_EDGES 600000
#define NT1B 1563   // k1 blocks: ceil(100000/64) node tiles of 64
#define NT2 9375    // k2 edge tiles of 64 (600000 = 9375*64 exactly)
#define LDH 136     // padded row stride (f16 elems), 16B-aligned rows
typedef _Float16 f16x8 __attribute__((ext_vector_type(8)));
typedef __attribute__((ext_vector_type(4))) float f32x4;

__device__ __forceinline__ float elu_f(float v) {
    return v > 0.0f ? v : (__expf(v) - 1.0f);
}

// k1: 64-node tiles, x staged to f16 ONCE, both output halves computed per tile.
// W1 frags for both halves in 64 VGPR; acc for both halves in 64 VGPR; shared
// A-frag reads (8 ds_read_b128 feed 16 MFMA per k-step).
extern "C" __global__ __launch_bounds__(256, 3)
void k1_node_linear(const float* __restrict__ x, const float* __restrict__ W1,
                    _Float16* __restrict__ P) {
    __shared__ __align__(16) _Float16 sX[64 * LDH];   // 17.4 KB

    const int t = threadIdx.x;
    const int w = t >> 6, lane = t & 63;
    const int ln = lane & 15, kg = lane >> 4;
    const int le = t >> 2;        // staging/store row 0..63
    const int q  = t & 3;         // 32-col chunk 0..3

    // W1 fragments, both halves, this wave's 32-col strip: 2*2*4*4 = 64 VGPR.
    f16x8 bf[2][2][4];
#pragma unroll
    for (int half = 0; half < 2; ++half)
#pragma unroll
        for (int c = 0; c < 2; ++c) {
            const int n = w * 32 + c * 16 + ln;
#pragma unroll
            for (int ks = 0; ks < 4; ++ks) {
                f16x8 v;
#pragma unroll
                for (int j = 0; j < 8; ++j) {
                    int k = half * 128 + ks * 32 + kg * 8 + j;
                    v[j] = (_Float16)W1[k * 128 + n];
                }
                bf[half][c][ks] = v;
            }
        }

    const int n0 = blockIdx.x * 64;

    // Stage x tile as f16 (single read of x).
    {
        int n = n0 + le;
#pragma unroll
        for (int i = 0; i < 4; ++i) {
            float4 a0 = make_float4(0.f, 0.f, 0.f, 0.f), a1 = a0;
            if (n < N_NODES) {
                const float* p = x + (size_t)n * 128 + q * 32 + i * 8;
                a0 = *(const float4*)p; a1 = *(const float4*)(p + 4);
            }
            f16x8 vh;
            vh[0] = (_Float16)a0.x; vh[1] = (_Float16)a0.y;
            vh[2] = (_Float16)a0.z; vh[3] = (_Float16)a0.w;
            vh[4] = (_Float16)a1.x; vh[5] = (_Float16)a1.y;
            vh[6] = (_Float16)a1.z; vh[7] = (_Float16)a1.w;
            *(f16x8*)(&sX[le * LDH + q * 32 + i * 8]) = vh;
        }
    }
    __syncthreads();

    // MFMA: both halves accumulated from shared A-frags.
    f32x4 acc[2][4][2];
#pragma unroll
    for (int half = 0; half < 2; ++half)
#pragma unroll
        for (int rt = 0; rt < 4; ++rt)
#pragma unroll
            for (int c = 0; c < 2; ++c) acc[half][rt][c] = (f32x4){0.f, 0.f, 0.f, 0.f};

#pragma unroll
    for (int ks = 0; ks < 4; ++ks) {
#pragma unroll
        for (int rt = 0; rt < 4; ++rt) {
            f16x8 a = *(const f16x8*)(&sX[(rt * 16 + ln) * LDH + ks * 32 + kg * 8]);
#pragma unroll
            for (int half = 0; half < 2; ++half)
#pragma unroll
                for (int c = 0; c < 2; ++c)
                    acc[half][rt][c] = __builtin_amdgcn_mfma_f32_16x16x32_f16(
                        a, bf[half][c][ks], acc[half][rt][c], 0, 0, 0);
        }
    }

    // Epilogue per half: bounce through sX (free after MFMA), coalesced f16 stores.
#pragma unroll
    for (int half = 0; half < 2; ++half) {
        __syncthreads();   // half0: MFMA reads done; half1: prior stores' reads done
#pragma unroll
        for (int rt = 0; rt < 4; ++rt)
#pragma unroll
            for (int c = 0; c < 2; ++c) {
                int col = w * 32 + c * 16 + ln;
#pragma unroll
                for (int reg = 0; reg < 4; ++reg) {
                    int row = rt * 16 + kg * 4 + reg;   // C-layout [m89/m91]
                    sX[row * LDH + col] = (_Float16)acc[half][rt][c][reg];
                }
            }
        __syncthreads();
        int n = n0 + le;
        if (n < N_NODES) {
            _Float16* dst = P + (size_t)n * 256 + half * 128 + q * 32;
            const _Float16* srcp = &sX[le * LDH + q * 32];
#pragma unroll
            for (int i = 0; i < 4; ++i)
                *(f16x8*)(dst + i * 8) = *(const f16x8*)(srcp + i * 8);
        }
    }
}

// k2: 64-edge tiles, single-barrier software pipeline through double-buffered LDS.
// Identical to R8 except occupancy 3->4 blocks/CU and grid 1024.
extern "C" __global__ __launch_bounds__(256, 4)
void k2_edge_mlp(const _Float16* __restrict__ P, const void* __restrict__ eiv,
                 const float* __restrict__ b1, const float* __restrict__ W2,
                 const float* __restrict__ b2, const float* __restrict__ W3,
                 const float* __restrict__ b3, float* __restrict__ out) {
    __shared__ __align__(16) _Float16 sH[2][64 * LDH];   // 34.8 KB
    __shared__ float sPart[2][4][64];                    // 2 KB
    __shared__ int sFlag;

    const int t = threadIdx.x;
    const int w = t >> 6, lane = t & 63;
    const int ln = lane & 15, kg = lane >> 4;
    const int row = t >> 2;          // staging row 0..63
    const int kc0 = (t & 3) * 4;     // staging k-chunk base (of 16 chunks/row)
    const float b3v = b3[0];
    const int stride = gridDim.x;

    if (t < 64) {
        unsigned v = ((const unsigned*)eiv)[2 * t + 1];
        unsigned long long bm = __ballot(v == 0u);
        if (t == 0) sFlag = (bm == ~0ull) ? 1 : 0;
    }

    f16x8 b1f[4];
#pragma unroll
    for (int i = 0; i < 4; ++i)
#pragma unroll
        for (int j = 0; j < 8; ++j) b1f[i][j] = (_Float16)b1[(kc0 + i) * 8 + j];

    float w3v[2], b2v[2];
#pragma unroll
    for (int c = 0; c < 2; ++c) {
        int col = w * 32 + c * 16 + ln;
        w3v[c] = W3[col]; b2v[c] = b2[col];
    }

    f16x8 bfw[2][4];
#pragma unroll
    for (int c = 0; c < 2; ++c) {
        const int n = w * 32 + c * 16 + ln;
#pragma unroll
        for (int ks = 0; ks < 4; ++ks) {
            f16x8 v;
#pragma unroll
            for (int j = 0; j < 8; ++j) {
                int k = ks * 32 + kg * 8 + j;
                v[j] = (_Float16)W2[k * 128 + n];
            }
            bfw[c][ks] = v;
        }
    }
    __syncthreads();
    const int mode64 = sFlag;

    const int tile0 = blockIdx.x;   // 1024 <= NT2 always

    int se_nx, ge_nx;
    {
        int e = tile0 * 64 + row;
        if (mode64) {
            se_nx = (int)((const long long*)eiv)[e];
            ge_nx = (int)((const long long*)eiv)[N_EDGES + e];
        } else {
            se_nx = ((const int*)eiv)[e];
            ge_nx = ((const int*)eiv)[N_EDGES + e];
        }
    }
    {
        const _Float16* pa = P + (size_t)se_nx * 256 + kc0 * 8;
        const _Float16* pb = P + (size_t)ge_nx * 256 + 128 + kc0 * 8;
        f16x8 Ga[4], Gb[4];
#pragma unroll
        for (int i = 0; i < 4; ++i) {
            Ga[i] = *(const f16x8*)(pa + i * 8);
            Gb[i] = *(const f16x8*)(pb + i * 8);
        }
#pragma unroll
        for (int i = 0; i < 4; ++i) {
            f16x8 vh;
#pragma unroll
            for (int j = 0; j < 8; ++j)
                vh[j] = (_Float16)elu_f((float)Ga[i][j] + (float)Gb[i][j] + (float)b1f[i][j]);
            *(f16x8*)(&sH[0][row * LDH + (kc0 + i) * 8]) = vh;
        }
    }
    {
        int t1 = tile0 + stride;
        int t1c = (t1 < NT2) ? t1 : tile0;
        int e = t1c * 64 + row;
        if (mode64) {
            se_nx = (int)((const long long*)eiv)[e];
            ge_nx = (int)((const long long*)eiv)[N_EDGES + e];
        } else {
            se_nx = ((const int*)eiv)[e];
            ge_nx = ((const int*)eiv)[N_EDGES + e];
        }
    }
    __syncthreads();   // sH[0] ready

    int p = 0;
    int prevE0 = -1;
    for (int tile = tile0; tile < NT2; tile += stride) {
        const int nt = tile + stride;
        const int ntc = (nt < NT2) ? nt : tile;

        // (1) Issue gathers for tile nt.
        const _Float16* pa = P + (size_t)se_nx * 256 + kc0 * 8;
        const _Float16* pb = P + (size_t)ge_nx * 256 + 128 + kc0 * 8;
        f16x8 Ga[4], Gb[4];
#pragma unroll
        for (int i = 0; i < 4; ++i) {
            Ga[i] = *(const f16x8*)(pa + i * 8);
            Gb[i] = *(const f16x8*)(pb + i * 8);
        }

        // (1b) Indices for tile nt+stride.
        {
            int n2 = nt + stride;
            int n2c = (n2 < NT2) ? n2 : ntc;
            int e = n2c * 64 + row;
            if (mode64) {
                se_nx = (int)((const long long*)eiv)[e];
                ge_nx = (int)((const long long*)eiv)[N_EDGES + e];
            } else {
                se_nx = ((const int*)eiv)[e];
                ge_nx = ((const int*)eiv)[N_EDGES + e];
            }
        }

        // (2) Out-write for the previous tile.
        if (prevE0 >= 0 && t < 64)
            out[prevE0 + t] = sPart[p ^ 1][0][t] + sPart[p ^ 1][1][t] +
                              sPart[p ^ 1][2][t] + sPart[p ^ 1][3][t] + b3v;

        // (3) MFMA on sH[p] + fused layer 3 -> sPart[p].
        f32x4 acc[4][2];
#pragma unroll
        for (int rt = 0; rt < 4; ++rt)
#pragma unroll
            for (int c = 0; c < 2; ++c) acc[rt][c] = (f32x4){0.f, 0.f, 0.f, 0.f};

#pragma unroll
        for (int ks = 0; ks < 4; ++ks) {
#pragma unroll
            for (int rt = 0; rt < 4; ++rt) {
                f16x8 a = *(const f16x8*)(&sH[p][(rt * 16 + ln) * LDH + ks * 32 + kg * 8]);
#pragma unroll
                for (int c = 0; c < 2; ++c)
                    acc[rt][c] = __builtin_amdgcn_mfma_f32_16x16x32_f16(a, bfw[c][ks], acc[rt][c], 0, 0, 0);
            }
        }

#pragma unroll
        for (int rt = 0; rt < 4; ++rt) {
            float pr[4] = {0.f, 0.f, 0.f, 0.f};
#pragma unroll
            for (int c = 0; c < 2; ++c) {
#pragma unroll
                for (int reg = 0; reg < 4; ++reg)
                    pr[reg] += elu_f(acc[rt][c][reg] + b2v[c]) * w3v[c];
            }
#pragma unroll
            for (int m = 1; m < 16; m <<= 1)
#pragma unroll
                for (int reg = 0; reg < 4; ++reg) pr[reg] += __shfl_xor(pr[reg], m, 64);
            if (ln == 0) {
#pragma unroll
                for (int reg = 0; reg < 4; ++reg)
                    sPart[p][w][rt * 16 + kg * 4 + reg] = pr[reg];
            }
        }

        // (4) Combine gathered tile nt -> sH[p^1].
#pragma unroll
        for (int i = 0; i < 4; ++i) {
            f16x8 vh;
#pragma unroll
            for (int j = 0; j < 8; ++j)
                vh[j] = (_Float16)elu_f((float)Ga[i][j] + (float)Gb[i][j] + (float)b1f[i][j]);
            *(f16x8*)(&sH[p ^ 1][row * LDH + (kc0 + i) * 8]) = vh;
        }

        prevE0 = tile * 64;
        __syncthreads();   // the ONLY per-tile barrier
        p ^= 1;
    }

    if (prevE0 >= 0 && t < 64)
        out[prevE0 + t] = sPart[p ^ 1][0][t] + sPart[p ^ 1][1][t] +
                          sPart[p ^ 1][2][t] + sPart[p ^ 1][3][t] + b3v;
}

extern "C" void kernel_launch(void* const* d_in, const int* in_sizes, int n_in,
                              void* d_out, int out_size, void* d_ws, size_t ws_size,
                              hipStream_t stream) {
    const float* x  = (const float*)d_in[0];
    const void*  ei = d_in[1];
    const float* W1 = (const float*)d_in[2];
    const float* b1 = (const float*)d_in[3];
    const float* W2 = (const float*)d_in[4];
    const float* b2 = (const float*)d_in[5];
    const float* W3 = (const float*)d_in[6];
    const float* b3 = (const float*)d_in[7];
    float* out = (float*)d_out;

    _Float16* P = (_Float16*)((char*)d_ws + 256);  // 100000*256 f16 = 51.2 MB

    k1_node_linear<<<NT1B, 256, 0, stream>>>(x, W1, P);
    k2_edge_mlp<<<1024, 256, 0, stream>>>(P, ei, b1, W2, b2, W3, b3, out);
}

// Round 10
// 196.668 us; speedup vs baseline: 1.3579x; 1.3579x over previous
//
#include <hip/hip_runtime.h>

#define N_NODES 100000
#define N_EDGES 600000
#define NT1B 1563   // k1 blocks: ceil(100000/64) node tiles of 64
#define NT2 9375    // k2 edge tiles of 64 (600000 = 9375*64 exactly)
#define LDH 136     // padded row stride (f16 elems), 16B-aligned rows
typedef _Float16 f16x8 __attribute__((ext_vector_type(8)));
typedef __attribute__((ext_vector_type(4))) float f32x4;

__device__ __forceinline__ float elu_f(float v) {
    return v > 0.0f ? v : (__expf(v) - 1.0f);
}

// k1: 64-node tiles, x staged to f16 ONCE, both output halves computed per tile.
// (R9 version — ~20 us faster than the 128-tile two-pass k1)
extern "C" __global__ __launch_bounds__(256, 3)
void k1_node_linear(const float* __restrict__ x, const float* __restrict__ W1,
                    _Float16* __restrict__ P) {
    __shared__ __align__(16) _Float16 sX[64 * LDH];   // 17.4 KB

    const int t = threadIdx.x;
    const int w = t >> 6, lane = t & 63;
    const int ln = lane & 15, kg = lane >> 4;
    const int le = t >> 2;        // staging/store row 0..63
    const int q  = t & 3;         // 32-col chunk 0..3

    // W1 fragments, both halves, this wave's 32-col strip: 64 VGPR.
    f16x8 bf[2][2][4];
#pragma unroll
    for (int half = 0; half < 2; ++half)
#pragma unroll
        for (int c = 0; c < 2; ++c) {
            const int n = w * 32 + c * 16 + ln;
#pragma unroll
            for (int ks = 0; ks < 4; ++ks) {
                f16x8 v;
#pragma unroll
                for (int j = 0; j < 8; ++j) {
                    int k = half * 128 + ks * 32 + kg * 8 + j;
                    v[j] = (_Float16)W1[k * 128 + n];
                }
                bf[half][c][ks] = v;
            }
        }

    const int n0 = blockIdx.x * 64;

    // Stage x tile as f16 (single read of x).
    {
        int n = n0 + le;
#pragma unroll
        for (int i = 0; i < 4; ++i) {
            float4 a0 = make_float4(0.f, 0.f, 0.f, 0.f), a1 = a0;
            if (n < N_NODES) {
                const float* p = x + (size_t)n * 128 + q * 32 + i * 8;
                a0 = *(const float4*)p; a1 = *(const float4*)(p + 4);
            }
            f16x8 vh;
            vh[0] = (_Float16)a0.x; vh[1] = (_Float16)a0.y;
            vh[2] = (_Float16)a0.z; vh[3] = (_Float16)a0.w;
            vh[4] = (_Float16)a1.x; vh[5] = (_Float16)a1.y;
            vh[6] = (_Float16)a1.z; vh[7] = (_Float16)a1.w;
            *(f16x8*)(&sX[le * LDH + q * 32 + i * 8]) = vh;
        }
    }
    __syncthreads();

    // MFMA: both halves accumulated from shared A-frags.
    f32x4 acc[2][4][2];
#pragma unroll
    for (int half = 0; half < 2; ++half)
#pragma unroll
        for (int rt = 0; rt < 4; ++rt)
#pragma unroll
            for (int c = 0; c < 2; ++c) acc[half][rt][c] = (f32x4){0.f, 0.f, 0.f, 0.f};

#pragma unroll
    for (int ks = 0; ks < 4; ++ks) {
#pragma unroll
        for (int rt = 0; rt < 4; ++rt) {
            f16x8 a = *(const f16x8*)(&sX[(rt * 16 + ln) * LDH + ks * 32 + kg * 8]);
#pragma unroll
            for (int half = 0; half < 2; ++half)
#pragma unroll
                for (int c = 0; c < 2; ++c)
                    acc[half][rt][c] = __builtin_amdgcn_mfma_f32_16x16x32_f16(
                        a, bf[half][c][ks], acc[half][rt][c], 0, 0, 0);
        }
    }

    // Epilogue per half: bounce through sX, coalesced f16 stores.
#pragma unroll
    for (int half = 0; half < 2; ++half) {
        __syncthreads();
#pragma unroll
        for (int rt = 0; rt < 4; ++rt)
#pragma unroll
            for (int c = 0; c < 2; ++c) {
                int col = w * 32 + c * 16 + ln;
#pragma unroll
                for (int reg = 0; reg < 4; ++reg) {
                    int row = rt * 16 + kg * 4 + reg;   // C-layout [m89/m91]
                    sX[row * LDH + col] = (_Float16)acc[half][rt][c][reg];
                }
            }
        __syncthreads();
        int n = n0 + le;
        if (n < N_NODES) {
            _Float16* dst = P + (size_t)n * 256 + half * 128 + q * 32;
            const _Float16* srcp = &sX[le * LDH + q * 32];
#pragma unroll
            for (int i = 0; i < 4; ++i)
                *(f16x8*)(dst + i * 8) = *(const f16x8*)(srcp + i * 8);
        }
    }
}

// k2: 64-edge tiles, single-barrier software pipeline through double-buffered LDS.
// EXACT R8 configuration: __launch_bounds__(256,3), grid 768, VGPR=84, no spill.
// (bounds 4 spills the Ga/Gb held set — verified regression in R9)
extern "C" __global__ __launch_bounds__(256, 3)
void k2_edge_mlp(const _Float16* __restrict__ P, const void* __restrict__ eiv,
                 const float* __restrict__ b1, const float* __restrict__ W2,
                 const float* __restrict__ b2, const float* __restrict__ W3,
                 const float* __restrict__ b3, float* __restrict__ out) {
    __shared__ __align__(16) _Float16 sH[2][64 * LDH];   // 34.8 KB
    __shared__ float sPart[2][4][64];                    // 2 KB
    __shared__ int sFlag;

    const int t = threadIdx.x;
    const int w = t >> 6, lane = t & 63;
    const int ln = lane & 15, kg = lane >> 4;
    const int row = t >> 2;          // staging row 0..63
    const int kc0 = (t & 3) * 4;     // staging k-chunk base (of 16 chunks/row)
    const float b3v = b3[0];
    const int stride = gridDim.x;

    if (t < 64) {
        unsigned v = ((const unsigned*)eiv)[2 * t + 1];
        unsigned long long bm = __ballot(v == 0u);
        if (t == 0) sFlag = (bm == ~0ull) ? 1 : 0;
    }

    f16x8 b1f[4];
#pragma unroll
    for (int i = 0; i < 4; ++i)
#pragma unroll
        for (int j = 0; j < 8; ++j) b1f[i][j] = (_Float16)b1[(kc0 + i) * 8 + j];

    float w3v[2], b2v[2];
#pragma unroll
    for (int c = 0; c < 2; ++c) {
        int col = w * 32 + c * 16 + ln;
        w3v[c] = W3[col]; b2v[c] = b2[col];
    }

    f16x8 bfw[2][4];
#pragma unroll
    for (int c = 0; c < 2; ++c) {
        const int n = w * 32 + c * 16 + ln;
#pragma unroll
        for (int ks = 0; ks < 4; ++ks) {
            f16x8 v;
#pragma unroll
            for (int j = 0; j < 8; ++j) {
                int k = ks * 32 + kg * 8 + j;
                v[j] = (_Float16)W2[k * 128 + n];
            }
            bfw[c][ks] = v;
        }
    }
    __syncthreads();
    const int mode64 = sFlag;

    const int tile0 = blockIdx.x;   // 768 <= NT2 always

    int se_nx, ge_nx;
    {
        int e = tile0 * 64 + row;
        if (mode64) {
            se_nx = (int)((const long long*)eiv)[e];
            ge_nx = (int)((const long long*)eiv)[N_EDGES + e];
        } else {
            se_nx = ((const int*)eiv)[e];
            ge_nx = ((const int*)eiv)[N_EDGES + e];
        }
    }
    {
        const _Float16* pa = P + (size_t)se_nx * 256 + kc0 * 8;
        const _Float16* pb = P + (size_t)ge_nx * 256 + 128 + kc0 * 8;
        f16x8 Ga[4], Gb[4];
#pragma unroll
        for (int i = 0; i < 4; ++i) {
            Ga[i] = *(const f16x8*)(pa + i * 8);
            Gb[i] = *(const f16x8*)(pb + i * 8);
        }
#pragma unroll
        for (int i = 0; i < 4; ++i) {
            f16x8 vh;
#pragma unroll
            for (int j = 0; j < 8; ++j)
                vh[j] = (_Float16)elu_f((float)Ga[i][j] + (float)Gb[i][j] + (float)b1f[i][j]);
            *(f16x8*)(&sH[0][row * LDH + (kc0 + i) * 8]) = vh;
        }
    }
    {
        int t1 = tile0 + stride;
        int t1c = (t1 < NT2) ? t1 : tile0;
        int e = t1c * 64 + row;
        if (mode64) {
            se_nx = (int)((const long long*)eiv)[e];
            ge_nx = (int)((const long long*)eiv)[N_EDGES + e];
        } else {
            se_nx = ((const int*)eiv)[e];
            ge_nx = ((const int*)eiv)[N_EDGES + e];
        }
    }
    __syncthreads();   // sH[0] ready

    int p = 0;
    int prevE0 = -1;
    for (int tile = tile0; tile < NT2; tile += stride) {
        const int nt = tile + stride;
        const int ntc = (nt < NT2) ? nt : tile;

        // (1) Issue gathers for tile nt.
        const _Float16* pa = P + (size_t)se_nx * 256 + kc0 * 8;
        const _Float16* pb = P + (size_t)ge_nx * 256 + 128 + kc0 * 8;
        f16x8 Ga[4], Gb[4];
#pragma unroll
        for (int i = 0; i < 4; ++i) {
            Ga[i] = *(const f16x8*)(pa + i * 8);
            Gb[i] = *(const f16x8*)(pb + i * 8);
        }

        // (1b) Indices for tile nt+stride.
        {
            int n2 = nt + stride;
            int n2c = (n2 < NT2) ? n2 : ntc;
            int e = n2c * 64 + row;
            if (mode64) {
                se_nx = (int)((const long long*)eiv)[e];
                ge_nx = (int)((const long long*)eiv)[N_EDGES + e];
            } else {
                se_nx = ((const int*)eiv)[e];
                ge_nx = ((const int*)eiv)[N_EDGES + e];
            }
        }

        // (2) Out-write for the previous tile.
        if (prevE0 >= 0 && t < 64)
            out[prevE0 + t] = sPart[p ^ 1][0][t] + sPart[p ^ 1][1][t] +
                              sPart[p ^ 1][2][t] + sPart[p ^ 1][3][t] + b3v;

        // (3) MFMA on sH[p] + fused layer 3 -> sPart[p].
        f32x4 acc[4][2];
#pragma unroll
        for (int rt = 0; rt < 4; ++rt)
#pragma unroll
            for (int c = 0; c < 2; ++c) acc[rt][c] = (f32x4){0.f, 0.f, 0.f, 0.f};

#pragma unroll
        for (int ks = 0; ks < 4; ++ks) {
#pragma unroll
            for (int rt = 0; rt < 4; ++rt) {
                f16x8 a = *(const f16x8*)(&sH[p][(rt * 16 + ln) * LDH + ks * 32 + kg * 8]);
#pragma unroll
                for (int c = 0; c < 2; ++c)
                    acc[rt][c] = __builtin_amdgcn_mfma_f32_16x16x32_f16(a, bfw[c][ks], acc[rt][c], 0, 0, 0);
            }
        }

#pragma unroll
        for (int rt = 0; rt < 4; ++rt) {
            float pr[4] = {0.f, 0.f, 0.f, 0.f};
#pragma unroll
            for (int c = 0; c < 2; ++c) {
#pragma unroll
                for (int reg = 0; reg < 4; ++reg)
                    pr[reg] += elu_f(acc[rt][c][reg] + b2v[c]) * w3v[c];
            }
#pragma unroll
            for (int m = 1; m < 16; m <<= 1)
#pragma unroll
                for (int reg = 0; reg < 4; ++reg) pr[reg] += __shfl_xor(pr[reg], m, 64);
            if (ln == 0) {
#pragma unroll
                for (int reg = 0; reg < 4; ++reg)
                    sPart[p][w][rt * 16 + kg * 4 + reg] = pr[reg];
            }
        }

        // (4) Combine gathered tile nt -> sH[p^1].
#pragma unroll
        for (int i = 0; i < 4; ++i) {
            f16x8 vh;
#pragma unroll
            for (int j = 0; j < 8; ++j)
                vh[j] = (_Float16)elu_f((float)Ga[i][j] + (float)Gb[i][j] + (float)b1f[i][j]);
            *(f16x8*)(&sH[p ^ 1][row * LDH + (kc0 + i) * 8]) = vh;
        }

        prevE0 = tile * 64;
        __syncthreads();   // the ONLY per-tile barrier
        p ^= 1;
    }

    if (prevE0 >= 0 && t < 64)
        out[prevE0 + t] = sPart[p ^ 1][0][t] + sPart[p ^ 1][1][t] +
                          sPart[p ^ 1][2][t] + sPart[p ^ 1][3][t] + b3v;
}

extern "C" void kernel_launch(void* const* d_in, const int* in_sizes, int n_in,
                              void* d_out, int out_size, void* d_ws, size_t ws_size,
                              hipStream_t stream) {
    const float* x  = (const float*)d_in[0];
    const void*  ei = d_in[1];
    const float* W1 = (const float*)d_in[2];
    const float* b1 = (const float*)d_in[3];
    const float* W2 = (const float*)d_in[4];
    const float* b2 = (const float*)d_in[5];
    const float* W3 = (const float*)d_in[6];
    const float* b3 = (const float*)d_in[7];
    float* out = (float*)d_out;

    _Float16* P = (_Float16*)((char*)d_ws + 256);  // 100000*256 f16 = 51.2 MB

    k1_node_linear<<<NT1B, 256, 0, stream>>>(x, W1, P);
    k2_edge_mlp<<<768, 256, 0, stream>>>(P, ei, b1, W2, b2, W3, b3, out);
}

// Round 11
// 192.784 us; speedup vs baseline: 1.3853x; 1.0201x over previous
//
#include <hip/hip_runtime.h>

#define N_NODES 100000
#define N_EDGES 600000
#define NT1 1563    // k1 node tiles of 64
#define NT2 9375    // k2 edge tiles of 64 (600000 = 9375*64 exactly)
#define LDH 136     // padded row stride (f16 elems), 16B-aligned rows
typedef _Float16 f16x8 __attribute__((ext_vector_type(8)));
typedef __attribute__((ext_vector_type(4))) float f32x4;

__device__ __forceinline__ float elu_f(float v) {
    return v > 0.0f ? v : (__expf(v) - 1.0f);
}

// k1: persistent (grid 768), 64-node tiles, x staged to f16 ONCE, both output
// halves per tile. W1 fragment set (64 VGPR) loaded ONCE per block and amortized
// over ~2 tiles (was: reloaded per tile in R10 — 128 strided scalar loads/thread).
extern "C" __global__ __launch_bounds__(256, 3)
void k1_node_linear(const float* __restrict__ x, const float* __restrict__ W1,
                    _Float16* __restrict__ P) {
    __shared__ __align__(16) _Float16 sX[64 * LDH];   // 17.4 KB

    const int t = threadIdx.x;
    const int w = t >> 6, lane = t & 63;
    const int ln = lane & 15, kg = lane >> 4;
    const int le = t >> 2;        // staging/store row 0..63
    const int q  = t & 3;         // 32-col chunk 0..3

    // W1 fragments, both halves, this wave's 32-col strip: 64 VGPR, loaded once.
    f16x8 bf[2][2][4];
#pragma unroll
    for (int half = 0; half < 2; ++half)
#pragma unroll
        for (int c = 0; c < 2; ++c) {
            const int n = w * 32 + c * 16 + ln;
#pragma unroll
            for (int ks = 0; ks < 4; ++ks) {
                f16x8 v;
#pragma unroll
                for (int j = 0; j < 8; ++j) {
                    int k = half * 128 + ks * 32 + kg * 8 + j;
                    v[j] = (_Float16)W1[k * 128 + n];
                }
                bf[half][c][ks] = v;
            }
        }

    for (int tile = blockIdx.x; tile < NT1; tile += gridDim.x) {
        const int n0 = tile * 64;
        __syncthreads();   // previous tile's epilogue reads of sX done

        // Stage x tile as f16 (single read of x).
        {
            int n = n0 + le;
#pragma unroll
            for (int i = 0; i < 4; ++i) {
                float4 a0 = make_float4(0.f, 0.f, 0.f, 0.f), a1 = a0;
                if (n < N_NODES) {
                    const float* p = x + (size_t)n * 128 + q * 32 + i * 8;
                    a0 = *(const float4*)p; a1 = *(const float4*)(p + 4);
                }
                f16x8 vh;
                vh[0] = (_Float16)a0.x; vh[1] = (_Float16)a0.y;
                vh[2] = (_Float16)a0.z; vh[3] = (_Float16)a0.w;
                vh[4] = (_Float16)a1.x; vh[5] = (_Float16)a1.y;
                vh[6] = (_Float16)a1.z; vh[7] = (_Float16)a1.w;
                *(f16x8*)(&sX[le * LDH + q * 32 + i * 8]) = vh;
            }
        }
        __syncthreads();

        // MFMA: both halves accumulated from shared A-frags.
        f32x4 acc[2][4][2];
#pragma unroll
        for (int half = 0; half < 2; ++half)
#pragma unroll
            for (int rt = 0; rt < 4; ++rt)
#pragma unroll
                for (int c = 0; c < 2; ++c) acc[half][rt][c] = (f32x4){0.f, 0.f, 0.f, 0.f};

#pragma unroll
        for (int ks = 0; ks < 4; ++ks) {
#pragma unroll
            for (int rt = 0; rt < 4; ++rt) {
                f16x8 a = *(const f16x8*)(&sX[(rt * 16 + ln) * LDH + ks * 32 + kg * 8]);
#pragma unroll
                for (int half = 0; half < 2; ++half)
#pragma unroll
                    for (int c = 0; c < 2; ++c)
                        acc[half][rt][c] = __builtin_amdgcn_mfma_f32_16x16x32_f16(
                            a, bf[half][c][ks], acc[half][rt][c], 0, 0, 0);
            }
        }

        // Epilogue per half: bounce through sX, coalesced f16 stores.
#pragma unroll
        for (int half = 0; half < 2; ++half) {
            __syncthreads();
#pragma unroll
            for (int rt = 0; rt < 4; ++rt)
#pragma unroll
                for (int c = 0; c < 2; ++c) {
                    int col = w * 32 + c * 16 + ln;
#pragma unroll
                    for (int reg = 0; reg < 4; ++reg) {
                        int row = rt * 16 + kg * 4 + reg;   // C-layout [m89/m91]
                        sX[row * LDH + col] = (_Float16)acc[half][rt][c][reg];
                    }
                }
            __syncthreads();
            int n = n0 + le;
            if (n < N_NODES) {
                _Float16* dst = P + (size_t)n * 256 + half * 128 + q * 32;
                const _Float16* srcp = &sX[le * LDH + q * 32];
#pragma unroll
                for (int i = 0; i < 4; ++i)
                    *(f16x8*)(dst + i * 8) = *(const f16x8*)(srcp + i * 8);
            }
        }
    }
}

// k2: 64-edge tiles, single-barrier software pipeline through double-buffered LDS.
// R8/R10-proven structure; change: h1 combine done in PACKED f16 (v_pk_add_f16) —
// f32 only inside the exp path of elu.
extern "C" __global__ __launch_bounds__(256, 3)
void k2_edge_mlp(const _Float16* __restrict__ P, const void* __restrict__ eiv,
                 const float* __restrict__ b1, const float* __restrict__ W2,
                 const float* __restrict__ b2, const float* __restrict__ W3,
                 const float* __restrict__ b3, float* __restrict__ out) {
    __shared__ __align__(16) _Float16 sH[2][64 * LDH];   // 34.8 KB
    __shared__ float sPart[2][4][64];                    // 2 KB
    __shared__ int sFlag;

    const int t = threadIdx.x;
    const int w = t >> 6, lane = t & 63;
    const int ln = lane & 15, kg = lane >> 4;
    const int row = t >> 2;          // staging row 0..63
    const int kc0 = (t & 3) * 4;     // staging k-chunk base (of 16 chunks/row)
    const float b3v = b3[0];
    const int stride = gridDim.x;

    if (t < 64) {
        unsigned v = ((const unsigned*)eiv)[2 * t + 1];
        unsigned long long bm = __ballot(v == 0u);
        if (t == 0) sFlag = (bm == ~0ull) ? 1 : 0;
    }

    f16x8 b1f[4];
#pragma unroll
    for (int i = 0; i < 4; ++i)
#pragma unroll
        for (int j = 0; j < 8; ++j) b1f[i][j] = (_Float16)b1[(kc0 + i) * 8 + j];

    float w3v[2], b2v[2];
#pragma unroll
    for (int c = 0; c < 2; ++c) {
        int col = w * 32 + c * 16 + ln;
        w3v[c] = W3[col]; b2v[c] = b2[col];
    }

    f16x8 bfw[2][4];
#pragma unroll
    for (int c = 0; c < 2; ++c) {
        const int n = w * 32 + c * 16 + ln;
#pragma unroll
        for (int ks = 0; ks < 4; ++ks) {
            f16x8 v;
#pragma unroll
            for (int j = 0; j < 8; ++j) {
                int k = ks * 32 + kg * 8 + j;
                v[j] = (_Float16)W2[k * 128 + n];
            }
            bfw[c][ks] = v;
        }
    }
    __syncthreads();
    const int mode64 = sFlag;

    const int tile0 = blockIdx.x;   // 768 <= NT2 always

    int se_nx, ge_nx;
    {
        int e = tile0 * 64 + row;
        if (mode64) {
            se_nx = (int)((const long long*)eiv)[e];
            ge_nx = (int)((const long long*)eiv)[N_EDGES + e];
        } else {
            se_nx = ((const int*)eiv)[e];
            ge_nx = ((const int*)eiv)[N_EDGES + e];
        }
    }
    {
        const _Float16* pa = P + (size_t)se_nx * 256 + kc0 * 8;
        const _Float16* pb = P + (size_t)ge_nx * 256 + 128 + kc0 * 8;
        f16x8 Ga[4], Gb[4];
#pragma unroll
        for (int i = 0; i < 4; ++i) {
            Ga[i] = *(const f16x8*)(pa + i * 8);
            Gb[i] = *(const f16x8*)(pb + i * 8);
        }
#pragma unroll
        for (int i = 0; i < 4; ++i) {
            f16x8 s = Ga[i] + Gb[i] + b1f[i];   // packed f16 adds
            f16x8 vh;
#pragma unroll
            for (int j = 0; j < 8; ++j) {
                _Float16 sv = s[j];
                vh[j] = (sv > (_Float16)0) ? sv
                        : (_Float16)(__expf((float)sv) - 1.0f);
            }
            *(f16x8*)(&sH[0][row * LDH + (kc0 + i) * 8]) = vh;
        }
    }
    {
        int t1 = tile0 + stride;
        int t1c = (t1 < NT2) ? t1 : tile0;
        int e = t1c * 64 + row;
        if (mode64) {
            se_nx = (int)((const long long*)eiv)[e];
            ge_nx = (int)((const long long*)eiv)[N_EDGES + e];
        } else {
            se_nx = ((const int*)eiv)[e];
            ge_nx = ((const int*)eiv)[N_EDGES + e];
        }
    }
    __syncthreads();   // sH[0] ready

    int p = 0;
    int prevE0 = -1;
    for (int tile = tile0; tile < NT2; tile += stride) {
        const int nt = tile + stride;
        const int ntc = (nt < NT2) ? nt : tile;

        // (1) Issue gathers for tile nt.
        const _Float16* pa = P + (size_t)se_nx * 256 + kc0 * 8;
        const _Float16* pb = P + (size_t)ge_nx * 256 + 128 + kc0 * 8;
        f16x8 Ga[4], Gb[4];
#pragma unroll
        for (int i = 0; i < 4; ++i) {
            Ga[i] = *(const f16x8*)(pa + i * 8);
            Gb[i] = *(const f16x8*)(pb + i * 8);
        }

        // (1b) Indices for tile nt+stride.
        {
            int n2 = nt + stride;
            int n2c = (n2 < NT2) ? n2 : ntc;
            int e = n2c * 64 + row;
            if (mode64) {
                se_nx = (int)((const long long*)eiv)[e];
                ge_nx = (int)((const long long*)eiv)[N_EDGES + e];
            } else {
                se_nx = ((const int*)eiv)[e];
                ge_nx = ((const int*)eiv)[N_EDGES + e];
            }
        }

        // (2) Out-write for the previous tile.
        if (prevE0 >= 0 && t < 64)
            out[prevE0 + t] = sPart[p ^ 1][0][t] + sPart[p ^ 1][1][t] +
                              sPart[p ^ 1][2][t] + sPart[p ^ 1][3][t] + b3v;

        // (3) MFMA on sH[p] + fused layer 3 -> sPart[p].
        f32x4 acc[4][2];
#pragma unroll
        for (int rt = 0; rt < 4; ++rt)
#pragma unroll
            for (int c = 0; c < 2; ++c) acc[rt][c] = (f32x4){0.f, 0.f, 0.f, 0.f};

#pragma unroll
        for (int ks = 0; ks < 4; ++ks) {
#pragma unroll
            for (int rt = 0; rt < 4; ++rt) {
                f16x8 a = *(const f16x8*)(&sH[p][(rt * 16 + ln) * LDH + ks * 32 + kg * 8]);
#pragma unroll
                for (int c = 0; c < 2; ++c)
                    acc[rt][c] = __builtin_amdgcn_mfma_f32_16x16x32_f16(a, bfw[c][ks], acc[rt][c], 0, 0, 0);
            }
        }

#pragma unroll
        for (int rt = 0; rt < 4; ++rt) {
            float pr[4] = {0.f, 0.f, 0.f, 0.f};
#pragma unroll
            for (int c = 0; c < 2; ++c) {
#pragma unroll
                for (int reg = 0; reg < 4; ++reg)
                    pr[reg] += elu_f(acc[rt][c][reg] + b2v[c]) * w3v[c];
            }
#pragma unroll
            for (int m = 1; m < 16; m <<= 1)
#pragma unroll
                for (int reg = 0; reg < 4; ++reg) pr[reg] += __shfl_xor(pr[reg], m, 64);
            if (ln == 0) {
#pragma unroll
                for (int reg = 0; reg < 4; ++reg)
                    sPart[p][w][rt * 16 + kg * 4 + reg] = pr[reg];
            }
        }

        // (4) Combine gathered tile nt -> sH[p^1] (packed f16 math).
#pragma unroll
        for (int i = 0; i < 4; ++i) {
            f16x8 s = Ga[i] + Gb[i] + b1f[i];   // v_pk_add_f16
            f16x8 vh;
#pragma unroll
            for (int j = 0; j < 8; ++j) {
                _Float16 sv = s[j];
                vh[j] = (sv > (_Float16)0) ? sv
                        : (_Float16)(__expf((float)sv) - 1.0f);
            }
            *(f16x8*)(&sH[p ^ 1][row * LDH + (kc0 + i) * 8]) = vh;
        }

        prevE0 = tile * 64;
        __syncthreads();   // the ONLY per-tile barrier
        p ^= 1;
    }

    if (prevE0 >= 0 && t < 64)
        out[prevE0 + t] = sPart[p ^ 1][0][t] + sPart[p ^ 1][1][t] +
                          sPart[p ^ 1][2][t] + sPart[p ^ 1][3][t] + b3v;
}

extern "C" void kernel_launch(void* const* d_in, const int* in_sizes, int n_in,
                              void* d_out, int out_size, void* d_ws, size_t ws_size,
                              hipStream_t stream) {
    const float* x  = (const float*)d_in[0];
    const void*  ei = d_in[1];
    const float* W1 = (const float*)d_in[2];
    const float* b1 = (const float*)d_in[3];
    const float* W2 = (const float*)d_in[4];
    const float* b2 = (const float*)d_in[5];
    const float* W3 = (const float*)d_in[6];
    const float* b3 = (const float*)d_in[7];
    float* out = (float*)d_out;

    _Float16* P = (_Float16*)((char*)d_ws + 256);  // 100000*256 f16 = 51.2 MB

    k1_node_linear<<<768, 256, 0, stream>>>(x, W1, P);
    k2_edge_mlp<<<768, 256, 0, stream>>>(P, ei, b1, W2, b2, W3, b3, out);
}